// Round 14
// baseline (569.938 us; speedup 1.0000x reference)
//
#include <hip/hip_runtime.h>

typedef __attribute__((ext_vector_type(8))) _Float16 half8;
typedef __attribute__((ext_vector_type(4))) _Float16 half4;
typedef __attribute__((ext_vector_type(2))) _Float16 half2;
typedef __attribute__((ext_vector_type(2))) __fp16 fp16x2;
typedef __attribute__((ext_vector_type(4))) float f32x4;

#define N_SEQ 4096
#define HD_QK 96
#define HD_V  64
#define NHEADS 8
// Q pre-scale = (256/8)^-0.5 * log2(e) -> scores in log2 domain
#define QSCALE 0.25505545556f
#define ESHIFT 8.0f

union PKC { fp16x2 p; half2 h; };

__device__ inline half2 pk_cvt(float a, float b) {
    PKC u;
    u.p = __builtin_amdgcn_cvt_pkrtz(a, b);
    return u.h;
}

__device__ inline half8 cvt8(float4 a, float4 b) {
    half8 h;
    h[0] = (_Float16)a.x; h[1] = (_Float16)a.y; h[2] = (_Float16)a.z; h[3] = (_Float16)a.w;
    h[4] = (_Float16)b.x; h[5] = (_Float16)b.y; h[6] = (_Float16)b.z; h[7] = (_Float16)b.w;
    return h;
}

__device__ inline void cast_blk(const float* __restrict__ in, _Float16* __restrict__ out,
                                int blk, int t) {
    size_t i = ((size_t)blk * 256 + t) * 8;
    float4 a = *(const float4*)(in + i);
    float4 b = *(const float4*)(in + i + 4);
    *(half8*)(out + i) = cvt8(a, b);
}

// 16B-per-lane global -> LDS DMA. LDS dest = uniform base + lane*16 (HW rule);
// global src is per-lane.
__device__ __forceinline__ void gl16(const void* g, void* l) {
    __builtin_amdgcn_global_load_lds(
        (const __attribute__((address_space(1))) unsigned int*)g,
        (__attribute__((address_space(3))) unsigned int*)l, 16, 0, 0);
}

// ---------------------------------------------------------------------------
// Prep (r12-exact; r13 proved the atomic row-sums are NOT a bottleneck):
//  [0,1536)     qk -> Xh f16
//  [1536,2560)  v_cls -> Vch f16
//  [2560,3712)  W_qk^T f16
//  [3712,3968)  W_v^T f16
//  [3968,8064)  masks -> swizzled f16 Msw (COALESCED writes) + Msum atomics
// Msw layout (halves), flash-r4-verbatim:
//   ((q0b*64+kb)*4 + w)*1024 + l15*64 + quad*16 + nt*4 + j
//   holds M[q0b*64 + 16nt + l15][kb*64 + 16w + 4quad + j]
// ---------------------------------------------------------------------------
__global__ __launch_bounds__(256) void prep(
    const float* __restrict__ qk, const float* __restrict__ v_cls,
    const float* __restrict__ masks, const float* __restrict__ W_qk,
    const float* __restrict__ W_v,
    _Float16* __restrict__ Xh, _Float16* __restrict__ Vch,
    _Float16* __restrict__ Msw, float* __restrict__ Msum,
    _Float16* __restrict__ Wqkt, _Float16* __restrict__ Wvt)
{
    __shared__ float tile[32][33];
    __shared__ float red[64][17];
    const int bx = blockIdx.x, t = threadIdx.x;
    if (bx < 1536) {
        cast_blk(qk, Xh, bx, t);
    } else if (bx < 2560) {
        cast_blk(v_cls, Vch, bx - 1536, t);
    } else if (bx < 3968) {
        const bool big = bx < 3712;
        const int id = big ? bx - 2560 : bx - 3712;
        const int nx = big ? 48 : 16;
        const int C = big ? 1536 : 512, R = big ? 768 : 512;
        const float* in = big ? W_qk : W_v;
        _Float16* out = big ? Wqkt : Wvt;
        int cx = id % nx, cy = id / nx;
        int tx = t & 31, ty = t >> 5;
        int c0 = cx * 32, r0 = cy * 32;
        for (int k = 0; k < 4; k++)
            tile[ty + 8 * k][tx] = in[(size_t)(r0 + ty + 8 * k) * C + c0 + tx];
        __syncthreads();
        for (int k = 0; k < 4; k++)
            out[(size_t)(c0 + ty + 8 * k) * R + r0 + tx] = (_Float16)tile[tx][ty + 8 * k];
    } else {
        const int id = bx - 3968;             // [0,4096): 64x64 mask tile
        const int q0b = id >> 6, kb = id & 63;
        const int w = t >> 6, lane = t & 63;
        const int l15 = lane >> 2, quad = lane & 3;
        const int col = kb * 64 + 16 * w + 4 * quad;
        half4 hv[4];
        float ps[4];
        for (int nt = 0; nt < 4; nt++) {
            const float* src = masks + (size_t)(q0b * 64 + 16 * nt + l15) * N_SEQ + col;
            float4 a = *(const float4*)src;
            hv[nt] = half4{(_Float16)a.x, (_Float16)a.y, (_Float16)a.z, (_Float16)a.w};
            ps[nt] = (a.x + a.y) + (a.z + a.w);
        }
        _Float16* dst = Msw + (((size_t)(q0b * 64 + kb) * 4 + w) * 1024) + lane * 16;
        half8 h0, h1;
        for (int j = 0; j < 4; j++) {
            h0[j] = hv[0][j]; h0[4 + j] = hv[1][j];
            h1[j] = hv[2][j]; h1[4 + j] = hv[3][j];
        }
        *(half8*)dst = h0;
        *(half8*)(dst + 8) = h1;
        for (int nt = 0; nt < 4; nt++)
            red[16 * nt + l15][w * 4 + quad] = ps[nt];
        __syncthreads();
        if (t < 64) {
            float s = 0.f;
            for (int i = 0; i < 16; i++) s += red[t][i];
            atomicAdd(&Msum[q0b * 64 + t], s);
        }
    }
}

// ---------------------------------------------------------------------------
// Fused projection GEMM (f16 in), 128x64 tile, BK=64.
// Grid 32x32 = 1024 blocks = 4 blocks/CU. acc 4x2 (32 AGPR), LDS 27.6 KB.
// blockIdx.x < 24: Xh@Wqkt^T (N=1536) -> Qh (xQSCALE) / Kh
// else:            Vch@Wvt^T (N=512)  -> Vtg[h][d][n]
// ---------------------------------------------------------------------------
__global__ __launch_bounds__(256) void proj_fused(
    const _Float16* __restrict__ Xh, const _Float16* __restrict__ Vch,
    const _Float16* __restrict__ Wqkt, const _Float16* __restrict__ Wvt,
    _Float16* __restrict__ Qh, _Float16* __restrict__ Kh,
    _Float16* __restrict__ Vtg)
{
    __shared__ _Float16 smem[192 * 72];   // Xs 128x72 + Ws 64x72 = 27.6 KB
    _Float16 (*Xs)[72] = (_Float16 (*)[72])smem;
    _Float16 (*Ws)[72] = (_Float16 (*)[72])(smem + 128 * 72);

    const int t = threadIdx.x;
    const int lane = t & 63, wv = t >> 6;
    const int quad = lane >> 4, l15 = lane & 15;
    const bool qkmode = blockIdx.x < 24;
    const int n0 = qkmode ? blockIdx.x * 64 : (blockIdx.x - 24) * 64;
    const int row0 = blockIdx.y * 128;
    const int K = qkmode ? 768 : 512;
    const _Float16* X = qkmode ? Xh : Vch;
    const _Float16* Wt = qkmode ? Wqkt : Wvt;

    const int mB = (wv & 1) * 64, nB = (wv >> 1) * 32;
    const int sr = t >> 1, sk = (t & 1) * 32;      // X stage: 128 rows x 64
    const int sr2 = t >> 2, sk2 = (t & 3) * 16;    // W stage: 64 rows x 64

    const f32x4 fzero = {0.f, 0.f, 0.f, 0.f};
    f32x4 acc[4][2];
    for (int i = 0; i < 4; i++)
        for (int j = 0; j < 2; j++) acc[i][j] = fzero;

    for (int k0 = 0; k0 < K; k0 += 64) {
        __syncthreads();
        {
            const _Float16* xp = X + (size_t)(row0 + sr) * K + k0 + sk;
            *(half8*)&Xs[sr][sk]      = *(const half8*)xp;
            *(half8*)&Xs[sr][sk + 8]  = *(const half8*)(xp + 8);
            *(half8*)&Xs[sr][sk + 16] = *(const half8*)(xp + 16);
            *(half8*)&Xs[sr][sk + 24] = *(const half8*)(xp + 24);
            const _Float16* wp = Wt + (size_t)(n0 + sr2) * K + k0 + sk2;
            *(half8*)&Ws[sr2][sk2]     = *(const half8*)wp;
            *(half8*)&Ws[sr2][sk2 + 8] = *(const half8*)(wp + 8);
        }
        __syncthreads();
        for (int c = 0; c < 2; c++) {
            half8 af[4], bf[2];
            for (int i = 0; i < 4; i++)
                af[i] = *(const half8*)&Xs[mB + 16 * i + l15][c * 32 + quad * 8];
            for (int j = 0; j < 2; j++)
                bf[j] = *(const half8*)&Ws[nB + 16 * j + l15][c * 32 + quad * 8];
            for (int i = 0; i < 4; i++)
                for (int j = 0; j < 2; j++)
                    acc[i][j] = __builtin_amdgcn_mfma_f32_16x16x32_f16(af[i], bf[j], acc[i][j], 0, 0, 0);
        }
    }

    __syncthreads();
    _Float16 (*Ct)[72] = (_Float16 (*)[72])smem;   // 128 x 72 f16 (reuse)
    for (int j = 0; j < 2; j++) {
        int col = n0 + nB + 16 * j + l15;
        float scl = (qkmode && col < 768) ? QSCALE : 1.0f;
        for (int i = 0; i < 4; i++)
            for (int r = 0; r < 4; r++)
                Ct[mB + 16 * i + quad * 4 + r][nB + 16 * j + l15] =
                    (_Float16)(acc[i][j][r] * scl);
    }
    __syncthreads();

    if (qkmode) {
        for (int e = 0; e < 4; e++) {
            int id = e * 256 + t;
            int row = id >> 3, cc = id & 7;       // 128 rows x 8 col-groups
            int col = n0 + cc * 8;
            int w = col >= 768 ? 1 : 0;
            int rem = col - w * 768;
            int h = rem / 96, d = rem - h * 96;
            _Float16* dst = w ? Kh : Qh;
            *(half8*)&dst[((size_t)h * N_SEQ + row0 + row) * HD_QK + d] =
                *(const half8*)&Ct[row][cc * 8];
        }
    } else {
        for (int e = 0; e < 2; e++) {
            int id = e * 256 + t;
            int col = id >> 3, rc = id & 7;       // 64 cols x 8 row-groups
            int c = n0 + col;
            int h = c >> 6, d = c & 63;
            half8 v0, v1;
            for (int k = 0; k < 8; k++) {
                v0[k] = Ct[rc * 16 + k][col];
                v1[k] = Ct[rc * 16 + 8 + k][col];
            }
            _Float16* dst = &Vtg[((size_t)h * HD_V + d) * N_SEQ + row0 + rc * 16];
            *(half8*)dst = v0;
            *(half8*)(dst + 8) = v1;
        }
    }
}

// ---------------------------------------------------------------------------
// Flash attention: r12 structure with K moved DMA->register A/B buffers at
// TRUE distance-2 (issued iter j, consumed iter j+2). Issue order per iter:
// [V-DMA(j+1)] [mask(j+1)] [K(j+2)] -- mask BEFORE K so the compiler's
// mask-wait at EXP does not force the in-flight K loads (in-order vmcnt).
// Top-of-iter s_waitcnt vmcnt(5) completes exactly {K(j) regs, V(j) DMA},
// leaving {mask(j) 2, K(j+1) 3}. Order pinned with sched_barrier(0).
// V stays DMA (scattered 64-row gather, needs per-lane-src DMA); LDS now
// V-only: 2 slots x 2KB x 4 waves = 16KB (epilogue 35.3KB alias on top).
// Loop unrolled x2 for static kfA/kfB + V-slot indices (rule #20).
// q0b-major XCD pinning; raw v_exp_f32; unclamped prefetch (reads pad).
// Regs ~96V+64A=160 <= 170 cap (3 blk/CU). -ESHIFT folded into MFMA C-init.
// ---------------------------------------------------------------------------
#define FA_STEP(KF, SLOT, J)                                                  \
    do {                                                                      \
        asm volatile("s_waitcnt vmcnt(5)" ::: "memory");                      \
        __builtin_amdgcn_sched_barrier(0);                                    \
        const char* vl_ = stW + (SLOT) * 2048 + (quad >> 1) * 1024            \
                          + l15 * 16 + (quad & 1) * 8;                        \
        half4 vf0 = *(const half4*)(vl_);                                     \
        half4 vf1 = *(const half4*)(vl_ + 256);                               \
        half4 vf2 = *(const half4*)(vl_ + 512);                               \
        half4 vf3 = *(const half4*)(vl_ + 768);                               \
        __builtin_amdgcn_sched_barrier(0);                                    \
        {                                                                     \
            const char* vs_ = vgb + (size_t)((J) + 1) * 128;                  \
            char* vd_ = stW + (1 - (SLOT)) * 2048;                            \
            gl16(vs_, vd_);                                                   \
            gl16(vs_ + 16, vd_ + 1024);                                       \
        }                                                                     \
        __builtin_amdgcn_sched_barrier(0);                                    \
        f32x4 sT[4];                                                          \
        for (int nt = 0; nt < 4; nt++) {                                      \
            f32x4 s = __builtin_amdgcn_mfma_f32_16x16x32_f16(KF[0], qf[0][nt], minit, 0, 0, 0); \
            s = __builtin_amdgcn_mfma_f32_16x16x32_f16(KF[1], qf[1][nt], s, 0, 0, 0); \
            s = __builtin_amdgcn_mfma_f32_16x16x32_f16(KF[2], qf[2][nt], s, 0, 0, 0); \
            sT[nt] = s;                                                       \
        }                                                                     \
        half4 af[4];                                                          \
        {                                                                     \
            half2 mh[8];                                                      \
            for (int i = 0; i < 4; i++) {                                     \
                mh[i]     = half2{m01[2 * i], m01[2 * i + 1]};                \
                mh[4 + i] = half2{m23[2 * i], m23[2 * i + 1]};                \
            }                                                                 \
            for (int nt = 0; nt < 4; nt++) {                                  \
                float p0 = __builtin_amdgcn_exp2f(sT[nt][0]);                 \
                float p1 = __builtin_amdgcn_exp2f(sT[nt][1]);                 \
                float p2 = __builtin_amdgcn_exp2f(sT[nt][2]);                 \
                float p3 = __builtin_amdgcn_exp2f(sT[nt][3]);                 \
                lsum[nt] += (p0 + p1) + (p2 + p3);                            \
                half2 lo = pk_cvt(p0, p1) * mh[2 * nt];                       \
                half2 hi = pk_cvt(p2, p3) * mh[2 * nt + 1];                   \
                af[nt] = half4{lo[0], lo[1], hi[0], hi[1]};                   \
            }                                                                 \
        }                                                                     \
        __builtin_amdgcn_sched_barrier(0);                                    \
        {                                                                     \
            const _Float16* mp_ = mbase + (size_t)((J) + 1 - kb0) * 4096;     \
            m01 = *(const half8*)mp_;                                         \
            m23 = *(const half8*)(mp_ + 8);                                   \
        }                                                                     \
        __builtin_amdgcn_sched_barrier(0);                                    \
        {                                                                     \
            const char* kp_ = kgb + (size_t)((J) + 2) * 12288;                \
            KF[0] = *(const half8*)(kp_);                                     \
            KF[1] = *(const half8*)(kp_ + 64);                                \
            KF[2] = *(const half8*)(kp_ + 128);                               \
        }                                                                     \
        __builtin_amdgcn_sched_barrier(0);                                    \
        for (int nt = 0; nt < 4; nt++) {                                      \
            oacc[nt][0] = __builtin_amdgcn_mfma_f32_16x16x16f16(af[nt], vf0, oacc[nt][0], 0, 0, 0); \
            oacc[nt][1] = __builtin_amdgcn_mfma_f32_16x16x16f16(af[nt], vf1, oacc[nt][1], 0, 0, 0); \
            oacc[nt][2] = __builtin_amdgcn_mfma_f32_16x16x16f16(af[nt], vf2, oacc[nt][2], 0, 0, 0); \
            oacc[nt][3] = __builtin_amdgcn_mfma_f32_16x16x16f16(af[nt], vf3, oacc[nt][3], 0, 0, 0); \
        }                                                                     \
    } while (0)

__global__ __launch_bounds__(256, 3) void flash_attn(
    const _Float16* __restrict__ Qh, const _Float16* __restrict__ Kh,
    const _Float16* __restrict__ Vtg, const _Float16* __restrict__ Msw,
    _Float16* __restrict__ Owsh, float* __restrict__ Lws)
{
    // V staging: per wave w at w*4096: slot s at s*2048 (16 KB total)
    // epilogue alias: Ob[2][64][68] f32 at 0 (34816 B), Lb[2][64] at 34816
    __shared__ __align__(16) char smem[35328];

    const int t = threadIdx.x;
    const int lane = t & 63, w = t >> 6;
    const int quad = lane >> 4, l15 = lane & 15;
    const int bx = blockIdx.x;
    const int q0b = bx & 63;
    const int hz = bx >> 6;
    const int head = hz & 7;
    const int z = hz >> 3;
    const int q0 = q0b * 64;
    const int kb0 = 21 * z, kbE = (z == 2) ? 64 : kb0 + 21;

    half8 qf[3][4];
    for (int nt = 0; nt < 4; nt++) {
        const _Float16* qp = Qh + ((size_t)head * N_SEQ + q0 + 16 * nt + l15) * HD_QK + 8 * quad;
        for (int c = 0; c < 3; c++)
            qf[c][nt] = *(const half8*)(qp + 32 * c);
    }

    // per-lane global source bases (bytes)
    const char* kgb = (const char*)Kh
        + ((size_t)(head * N_SEQ + 16 * w + l15) * HD_QK + 8 * quad) * 2;
    const char* vgb = (const char*)Vtg
        + ((size_t)(head * HD_V + lane) * N_SEQ) * 2 + 32 * w;
    const _Float16* mbase = Msw + ((size_t)(q0b * 64 + kb0) * 4 + w) * 1024
                                + (l15 * 4 + quad) * 16;

    char* stW = smem + w * 4096;   // this wave's V staging (2 slots)

    const f32x4 fzero = {0.f, 0.f, 0.f, 0.f};
    const f32x4 minit = {-ESHIFT, -ESHIFT, -ESHIFT, -ESHIFT};
    f32x4 oacc[4][4];
    for (int nt = 0; nt < 4; nt++)
        for (int v = 0; v < 4; v++) oacc[nt][v] = fzero;
    float lsum[4] = {0.f, 0.f, 0.f, 0.f};

    half8 kfA[3], kfB[3];
    half8 m01, m23;

    // Prologue — ISSUE ORDER (vmcnt accounting): [kfA 3][V-DMA 2][mask 2][kfB 3]
    {
        const char* kp = kgb + (size_t)kb0 * 12288;
        kfA[0] = *(const half8*)(kp);
        kfA[1] = *(const half8*)(kp + 64);
        kfA[2] = *(const half8*)(kp + 128);
    }
    __builtin_amdgcn_sched_barrier(0);
    {
        const char* vs = vgb + (size_t)kb0 * 128;
        gl16(vs, stW);
        gl16(vs + 16, stW + 1024);
    }
    __builtin_amdgcn_sched_barrier(0);
    m01 = *(const half8*)mbase;
    m23 = *(const half8*)(mbase + 8);
    __builtin_amdgcn_sched_barrier(0);
    {
        const char* kp = kgb + (size_t)(kb0 + 1) * 12288;
        kfB[0] = *(const half8*)(kp);
        kfB[1] = *(const half8*)(kp + 64);
        kfB[2] = *(const half8*)(kp + 128);
    }
    __builtin_amdgcn_sched_barrier(0);

    int j = kb0;
    for (; j + 1 < kbE; j += 2) {
        FA_STEP(kfA, 0, j);
        FA_STEP(kfB, 1, j + 1);
    }
    if (j < kbE) {
        FA_STEP(kfA, 0, j);
    }

    // Alias boundary: all waves done with staging LDS before Ob/Lb reuse.
    // (__syncthreads drains vmcnt(0) -> pending tail DMAs land before reuse.)
    __syncthreads();

    float (*Ob)[64][68] = (float (*)[64][68])smem;
    float (*Lb)[64] = (float (*)[64])(smem + 34816);

    for (int nt = 0; nt < 4; nt++) {
        lsum[nt] += __shfl_xor(lsum[nt], 16);
        lsum[nt] += __shfl_xor(lsum[nt], 32);
    }

    if (w & 1) {
        for (int nt = 0; nt < 4; nt++) {
            for (int v = 0; v < 4; v++)
                for (int r = 0; r < 4; r++)
                    Ob[w >> 1][16 * nt + 4 * quad + r][16 * v + l15] = oacc[nt][v][r];
            if (quad == 0) Lb[w >> 1][16 * nt + l15] = lsum[nt];
        }
    }
    __syncthreads();
    if (!(w & 1)) {
        for (int nt = 0; nt < 4; nt++) {
            for (int v = 0; v < 4; v++)
                for (int r = 0; r < 4; r++)
                    Ob[w >> 1][16 * nt + 4 * quad + r][16 * v + l15] += oacc[nt][v][r];
            if (quad == 0) Lb[w >> 1][16 * nt + l15] += lsum[nt];
        }
    }
    __syncthreads();

    {
        int row = t >> 2, c0 = (t & 3) * 16;
        _Float16* obase = Owsh + (size_t)z * N_SEQ * 512 + (size_t)(q0 + row) * 512
                          + head * HD_V + c0;
        for (int g = 0; g < 2; g++) {
            half8 h;
            for (int j2 = 0; j2 < 8; j2++)
                h[j2] = (_Float16)(Ob[0][row][c0 + 8 * g + j2] + Ob[1][row][c0 + 8 * g + j2]);
            *(half8*)(obase + 8 * g) = h;
        }
        if (t < 64)
            Lws[((size_t)z * NHEADS + head) * N_SEQ + q0 + t] = Lb[0][t] + Lb[1][t];
    }
}

#undef FA_STEP

// ---------------------------------------------------------------------------
// Finalize: out = sum_z O_z / (sum_z l_z * H * Msum[q])
// ---------------------------------------------------------------------------
__global__ __launch_bounds__(256) void finalize(
    const _Float16* __restrict__ Owsh, const float* __restrict__ Lws,
    const float* __restrict__ Msum, float* __restrict__ out)
{
    const size_t ZSTR = (size_t)N_SEQ * 512;
    size_t o = ((size_t)blockIdx.x * 256 + threadIdx.x) * 8;
    int q = (int)(o >> 9);
    int head = (int)((o & 511) >> 6);
    half8 p0 = *(const half8*)(Owsh + o);
    half8 p1 = *(const half8*)(Owsh + ZSTR + o);
    half8 p2 = *(const half8*)(Owsh + 2 * ZSTR + o);
    float l = Lws[(size_t)head * N_SEQ + q]
            + Lws[((size_t)NHEADS + head) * N_SEQ + q]
            + Lws[((size_t)2 * NHEADS + head) * N_SEQ + q];
    float inv = 1.0f / (l * (float)NHEADS * Msum[q]);
    float4 r0, r1;
    r0.x = ((float)p0[0] + (float)p1[0] + (float)p2[0]) * inv;
    r0.y = ((float)p0[1] + (float)p1[1] + (float)p2[1]) * inv;
    r0.z = ((float)p0[2] + (float)p1[2] + (float)p2[2]) * inv;
    r0.w = ((float)p0[3] + (float)p1[3] + (float)p2[3]) * inv;
    r1.x = ((float)p0[4] + (float)p1[4] + (float)p2[4]) * inv;
    r1.y = ((float)p0[5] + (float)p1[5] + (float)p2[5]) * inv;
    r1.z = ((float)p0[6] + (float)p1[6] + (float)p2[6]) * inv;
    r1.w = ((float)p0[7] + (float)p1[7] + (float)p2[7]) * inv;
    *(float4*)(out + o) = r0;
    *(float4*)(out + o + 4) = r1;
}

extern "C" void kernel_launch(void* const* d_in, const int* in_sizes, int n_in,
                              void* d_out, int out_size, void* d_ws, size_t ws_size,
                              hipStream_t stream) {
    const float* qk    = (const float*)d_in[0];
    const float* v_cls = (const float*)d_in[1];
    const float* masks = (const float*)d_in[2];
    const float* W_qk  = (const float*)d_in[3];
    const float* W_v   = (const float*)d_in[4];
    float* out = (float*)d_out;

    char* wsp = (char*)d_ws;
    // region0 [0, 13 MB): prep-stage buffers, later aliased by Owsh (12.6 MB)
    _Float16* Xh   = (_Float16*)(wsp);                         // 6.0 MB
    _Float16* Vch  = (_Float16*)(wsp + (size_t)6291456);       // 4.0 MB
    _Float16* Wqkt = (_Float16*)(wsp + (size_t)10485760);      // 2.25 MB
    _Float16* Wvt  = (_Float16*)(wsp + (size_t)12845056);      // 0.5 MB
    _Float16* Owsh = (_Float16*)(wsp);                         // 3*4096*512*2 = 12.58 MB
    size_t off = 13631488;                                     // 13 MB
    auto allocB = [&](size_t bytes) { char* p = wsp + off; off += (bytes + 255) & ~(size_t)255; return p; };
    _Float16* Qh   = (_Float16*)allocB((size_t)NHEADS * N_SEQ * HD_QK * 2);
    _Float16* Kh   = (_Float16*)allocB((size_t)NHEADS * N_SEQ * HD_QK * 2);
    _Float16* Vtg  = (_Float16*)allocB((size_t)NHEADS * HD_V * N_SEQ * 2);
    _Float16* Msw  = (_Float16*)allocB((size_t)N_SEQ * N_SEQ * 2);
    float*    Msum = (float*)allocB((size_t)N_SEQ * 4);
    float*    Lws  = (float*)allocB((size_t)3 * NHEADS * N_SEQ * 4);
    // tail pad: unclamped K/V/mask prefetches may read up to ~64KB past
    // their buffers (K j+2, V j+1, mask j+1) -- keep them inside workspace.
    (void)allocB((size_t)131072);
    (void)ws_size;

    dim3 blk(256);
    (void)hipMemsetAsync(Msum, 0, N_SEQ * sizeof(float), stream);
    prep<<<dim3(8064), blk, 0, stream>>>(
        qk, v_cls, masks, W_qk, W_v, Xh, Vch, Msw, Msum, Wqkt, Wvt);

    proj_fused<<<dim3(32, N_SEQ / 128), blk, 0, stream>>>(
        Xh, Vch, Wqkt, Wvt, Qh, Kh, Vtg);

    flash_attn<<<dim3(1536), blk, 0, stream>>>(
        Qh, Kh, Vtg, Msw, Owsh, Lws);

    finalize<<<dim3((N_SEQ * 512) / (256 * 8)), blk, 0, stream>>>(
        Owsh, Lws, Msum, out);
}

// Round 15
// 314.658 us; speedup vs baseline: 1.8113x; 1.8113x over previous
//
#include <hip/hip_runtime.h>

typedef __attribute__((ext_vector_type(8))) _Float16 half8;
typedef __attribute__((ext_vector_type(4))) _Float16 half4;
typedef __attribute__((ext_vector_type(2))) _Float16 half2;
typedef __attribute__((ext_vector_type(2))) __fp16 fp16x2;
typedef __attribute__((ext_vector_type(4))) float f32x4;

#define N_SEQ 4096
#define HD_QK 96
#define HD_V  64
#define NHEADS 8
// Q pre-scale = (256/8)^-0.5 * log2(e) -> scores in log2 domain
#define QSCALE 0.25505545556f
#define ESHIFT 8.0f

union PKC { fp16x2 p; half2 h; };

__device__ inline half2 pk_cvt(float a, float b) {
    PKC u;
    u.p = __builtin_amdgcn_cvt_pkrtz(a, b);
    return u.h;
}

__device__ inline half8 cvt8(float4 a, float4 b) {
    half8 h;
    h[0] = (_Float16)a.x; h[1] = (_Float16)a.y; h[2] = (_Float16)a.z; h[3] = (_Float16)a.w;
    h[4] = (_Float16)b.x; h[5] = (_Float16)b.y; h[6] = (_Float16)b.z; h[7] = (_Float16)b.w;
    return h;
}

__device__ inline void cast_blk(const float* __restrict__ in, _Float16* __restrict__ out,
                                int blk, int t) {
    size_t i = ((size_t)blk * 256 + t) * 8;
    float4 a = *(const float4*)(in + i);
    float4 b = *(const float4*)(in + i + 4);
    *(half8*)(out + i) = cvt8(a, b);
}

// 16B-per-lane global -> LDS DMA. LDS dest = uniform base + lane*16 (HW rule);
// global src is per-lane.
__device__ __forceinline__ void gl16(const void* g, void* l) {
    __builtin_amdgcn_global_load_lds(
        (const __attribute__((address_space(1))) unsigned int*)g,
        (__attribute__((address_space(3))) unsigned int*)l, 16, 0, 0);
}

// ---------------------------------------------------------------------------
// Prep (r12-exact):
//  [0,1536)     qk -> Xh f16
//  [1536,2560)  v_cls -> Vch f16
//  [2560,3712)  W_qk^T f16
//  [3712,3968)  W_v^T f16
//  [3968,8064)  masks -> swizzled f16 Msw (COALESCED writes) + Msum atomics
// Msw layout (halves), flash-r4-verbatim:
//   ((q0b*64+kb)*4 + w)*1024 + l15*64 + quad*16 + nt*4 + j
//   holds M[q0b*64 + 16nt + l15][kb*64 + 16w + 4quad + j]
// ---------------------------------------------------------------------------
__global__ __launch_bounds__(256) void prep(
    const float* __restrict__ qk, const float* __restrict__ v_cls,
    const float* __restrict__ masks, const float* __restrict__ W_qk,
    const float* __restrict__ W_v,
    _Float16* __restrict__ Xh, _Float16* __restrict__ Vch,
    _Float16* __restrict__ Msw, float* __restrict__ Msum,
    _Float16* __restrict__ Wqkt, _Float16* __restrict__ Wvt)
{
    __shared__ float tile[32][33];
    __shared__ float red[64][17];
    const int bx = blockIdx.x, t = threadIdx.x;
    if (bx < 1536) {
        cast_blk(qk, Xh, bx, t);
    } else if (bx < 2560) {
        cast_blk(v_cls, Vch, bx - 1536, t);
    } else if (bx < 3968) {
        const bool big = bx < 3712;
        const int id = big ? bx - 2560 : bx - 3712;
        const int nx = big ? 48 : 16;
        const int C = big ? 1536 : 512, R = big ? 768 : 512;
        const float* in = big ? W_qk : W_v;
        _Float16* out = big ? Wqkt : Wvt;
        int cx = id % nx, cy = id / nx;
        int tx = t & 31, ty = t >> 5;
        int c0 = cx * 32, r0 = cy * 32;
        for (int k = 0; k < 4; k++)
            tile[ty + 8 * k][tx] = in[(size_t)(r0 + ty + 8 * k) * C + c0 + tx];
        __syncthreads();
        for (int k = 0; k < 4; k++)
            out[(size_t)(c0 + ty + 8 * k) * R + r0 + tx] = (_Float16)tile[tx][ty + 8 * k];
    } else {
        const int id = bx - 3968;             // [0,4096): 64x64 mask tile
        const int q0b = id >> 6, kb = id & 63;
        const int w = t >> 6, lane = t & 63;
        const int l15 = lane >> 2, quad = lane & 3;
        const int col = kb * 64 + 16 * w + 4 * quad;
        half4 hv[4];
        float ps[4];
        for (int nt = 0; nt < 4; nt++) {
            const float* src = masks + (size_t)(q0b * 64 + 16 * nt + l15) * N_SEQ + col;
            float4 a = *(const float4*)src;
            hv[nt] = half4{(_Float16)a.x, (_Float16)a.y, (_Float16)a.z, (_Float16)a.w};
            ps[nt] = (a.x + a.y) + (a.z + a.w);
        }
        _Float16* dst = Msw + (((size_t)(q0b * 64 + kb) * 4 + w) * 1024) + lane * 16;
        half8 h0, h1;
        for (int j = 0; j < 4; j++) {
            h0[j] = hv[0][j]; h0[4 + j] = hv[1][j];
            h1[j] = hv[2][j]; h1[4 + j] = hv[3][j];
        }
        *(half8*)dst = h0;
        *(half8*)(dst + 8) = h1;
        for (int nt = 0; nt < 4; nt++)
            red[16 * nt + l15][w * 4 + quad] = ps[nt];
        __syncthreads();
        if (t < 64) {
            float s = 0.f;
            for (int i = 0; i < 16; i++) s += red[t][i];
            atomicAdd(&Msum[q0b * 64 + t], s);
        }
    }
}

// ---------------------------------------------------------------------------
// Fused projection GEMM (f16 in), 128x64 tile, BK=64.
// Grid 32x32 = 1024 blocks = 4 blocks/CU. acc 4x2 (32 AGPR), LDS 27.6 KB.
// blockIdx.x < 24: Xh@Wqkt^T (N=1536) -> Qh (xQSCALE) / Kh
// else:            Vch@Wvt^T (N=512)  -> Vtg[h][d][n]
// ---------------------------------------------------------------------------
__global__ __launch_bounds__(256) void proj_fused(
    const _Float16* __restrict__ Xh, const _Float16* __restrict__ Vch,
    const _Float16* __restrict__ Wqkt, const _Float16* __restrict__ Wvt,
    _Float16* __restrict__ Qh, _Float16* __restrict__ Kh,
    _Float16* __restrict__ Vtg)
{
    __shared__ _Float16 smem[192 * 72];   // Xs 128x72 + Ws 64x72 = 27.6 KB
    _Float16 (*Xs)[72] = (_Float16 (*)[72])smem;
    _Float16 (*Ws)[72] = (_Float16 (*)[72])(smem + 128 * 72);

    const int t = threadIdx.x;
    const int lane = t & 63, wv = t >> 6;
    const int quad = lane >> 4, l15 = lane & 15;
    const bool qkmode = blockIdx.x < 24;
    const int n0 = qkmode ? blockIdx.x * 64 : (blockIdx.x - 24) * 64;
    const int row0 = blockIdx.y * 128;
    const int K = qkmode ? 768 : 512;
    const _Float16* X = qkmode ? Xh : Vch;
    const _Float16* Wt = qkmode ? Wqkt : Wvt;

    const int mB = (wv & 1) * 64, nB = (wv >> 1) * 32;
    const int sr = t >> 1, sk = (t & 1) * 32;      // X stage: 128 rows x 64
    const int sr2 = t >> 2, sk2 = (t & 3) * 16;    // W stage: 64 rows x 64

    const f32x4 fzero = {0.f, 0.f, 0.f, 0.f};
    f32x4 acc[4][2];
    for (int i = 0; i < 4; i++)
        for (int j = 0; j < 2; j++) acc[i][j] = fzero;

    for (int k0 = 0; k0 < K; k0 += 64) {
        __syncthreads();
        {
            const _Float16* xp = X + (size_t)(row0 + sr) * K + k0 + sk;
            *(half8*)&Xs[sr][sk]      = *(const half8*)xp;
            *(half8*)&Xs[sr][sk + 8]  = *(const half8*)(xp + 8);
            *(half8*)&Xs[sr][sk + 16] = *(const half8*)(xp + 16);
            *(half8*)&Xs[sr][sk + 24] = *(const half8*)(xp + 24);
            const _Float16* wp = Wt + (size_t)(n0 + sr2) * K + k0 + sk2;
            *(half8*)&Ws[sr2][sk2]     = *(const half8*)wp;
            *(half8*)&Ws[sr2][sk2 + 8] = *(const half8*)(wp + 8);
        }
        __syncthreads();
        for (int c = 0; c < 2; c++) {
            half8 af[4], bf[2];
            for (int i = 0; i < 4; i++)
                af[i] = *(const half8*)&Xs[mB + 16 * i + l15][c * 32 + quad * 8];
            for (int j = 0; j < 2; j++)
                bf[j] = *(const half8*)&Ws[nB + 16 * j + l15][c * 32 + quad * 8];
            for (int i = 0; i < 4; i++)
                for (int j = 0; j < 2; j++)
                    acc[i][j] = __builtin_amdgcn_mfma_f32_16x16x32_f16(af[i], bf[j], acc[i][j], 0, 0, 0);
        }
    }

    __syncthreads();
    _Float16 (*Ct)[72] = (_Float16 (*)[72])smem;   // 128 x 72 f16 (reuse)
    for (int j = 0; j < 2; j++) {
        int col = n0 + nB + 16 * j + l15;
        float scl = (qkmode && col < 768) ? QSCALE : 1.0f;
        for (int i = 0; i < 4; i++)
            for (int r = 0; r < 4; r++)
                Ct[mB + 16 * i + quad * 4 + r][nB + 16 * j + l15] =
                    (_Float16)(acc[i][j][r] * scl);
    }
    __syncthreads();

    if (qkmode) {
        for (int e = 0; e < 4; e++) {
            int id = e * 256 + t;
            int row = id >> 3, cc = id & 7;       // 128 rows x 8 col-groups
            int col = n0 + cc * 8;
            int w = col >= 768 ? 1 : 0;
            int rem = col - w * 768;
            int h = rem / 96, d = rem - h * 96;
            _Float16* dst = w ? Kh : Qh;
            *(half8*)&dst[((size_t)h * N_SEQ + row0 + row) * HD_QK + d] =
                *(const half8*)&Ct[row][cc * 8];
        }
    } else {
        for (int e = 0; e < 2; e++) {
            int id = e * 256 + t;
            int col = id >> 3, rc = id & 7;       // 64 cols x 8 row-groups
            int c = n0 + col;
            int h = c >> 6, d = c & 63;
            half8 v0, v1;
            for (int k = 0; k < 8; k++) {
                v0[k] = Ct[rc * 16 + k][col];
                v1[k] = Ct[rc * 16 + 8 + k][col];
            }
            _Float16* dst = &Vtg[((size_t)h * HD_V + d) * N_SEQ + row0 + rc * 16];
            *(half8*)dst = v0;
            *(half8*)(dst + 8) = v1;
        }
    }
}

// ---------------------------------------------------------------------------
// Flash attention: r12 structure with K TRIPLE-BUFFERED IN LDS (distance-2
// lead through the proven global_load_lds path -- NO new register state;
// r1/r3/r14 proved register-held prefetch always spills). Per-iter VMEM
// issue order: [V(j+1) DMA 2][mask(j+1) regs 2][K(j+2) DMA 3]. In-order
// vmcnt queue at top of iter j = [K(j)3, V(j)2, mask(j)2, K(j+1)3]; the
// single s_waitcnt vmcnt(3) completes exactly {K(j), V(j), mask(j)} while
// K(j+1) stays in flight. mh[8] (tile-j mask unpack) is hoisted ABOVE the
// mask(j+1) register loads so m01/m23 can be reused as the j+1 buffer.
// LDS/wave: K 3x3072 + V 2x2048 = 13312 B; block 53248 B; 3 blocks = 156KB
// <= 160KB -> occupancy unchanged. Slot indices (%3, ^1) are runtime but
// address-only (no register-array indexing -> no spill vector).
// q0b-major XCD pinning; raw v_exp_f32; unclamped prefetch (reads pad).
// -ESHIFT folded into MFMA C-init; p = exp2(s') exact.
// ---------------------------------------------------------------------------
__global__ __launch_bounds__(256, 3) void flash_attn(
    const _Float16* __restrict__ Qh, const _Float16* __restrict__ Kh,
    const _Float16* __restrict__ Vtg, const _Float16* __restrict__ Msw,
    _Float16* __restrict__ Owsh, float* __restrict__ Lws)
{
    // per wave w at w*13312: K slots s*3072 (s=0..2), V slots 9216+c*2048
    // epilogue alias: Ob[2][64][68] f32 at 0 (34816 B), Lb[2][64] at 34816
    __shared__ __align__(16) char smem[53248];

    const int t = threadIdx.x;
    const int lane = t & 63, w = t >> 6;
    const int quad = lane >> 4, l15 = lane & 15;
    const int bx = blockIdx.x;
    const int q0b = bx & 63;
    const int hz = bx >> 6;
    const int head = hz & 7;
    const int z = hz >> 3;
    const int q0 = q0b * 64;
    const int kb0 = 21 * z, kbE = (z == 2) ? 64 : kb0 + 21;

    half8 qf[3][4];
    for (int nt = 0; nt < 4; nt++) {
        const _Float16* qp = Qh + ((size_t)head * N_SEQ + q0 + 16 * nt + l15) * HD_QK + 8 * quad;
        for (int c = 0; c < 3; c++)
            qf[c][nt] = *(const half8*)(qp + 32 * c);
    }

    // per-lane global source bases (bytes)
    const char* kgb = (const char*)Kh
        + ((size_t)(head * N_SEQ + 16 * w + l15) * HD_QK + 8 * quad) * 2;
    const char* vgb = (const char*)Vtg
        + ((size_t)(head * HD_V + lane) * N_SEQ) * 2 + 32 * w;
    const _Float16* mbase = Msw + ((size_t)(q0b * 64 + kb0) * 4 + w) * 1024
                                + (l15 * 4 + quad) * 16;

    char* stW = smem + w * 13312;    // this wave's staging
    char* stV = stW + 9216;          // V slots

    const f32x4 fzero = {0.f, 0.f, 0.f, 0.f};
    const f32x4 minit = {-ESHIFT, -ESHIFT, -ESHIFT, -ESHIFT};
    f32x4 oacc[4][4];
    for (int nt = 0; nt < 4; nt++)
        for (int v = 0; v < 4; v++) oacc[nt][v] = fzero;
    float lsum[4] = {0.f, 0.f, 0.f, 0.f};

    half8 m01, m23;

    // Prologue — ISSUE ORDER (vmcnt queue): [K(kb0) 3][V(kb0) 2][mask(kb0) 2][K(kb0+1) 3]
    {
        const char* ks = kgb + (size_t)kb0 * 12288;
        gl16(ks, stW);
        gl16(ks + 64, stW + 1024);
        gl16(ks + 128, stW + 2048);
    }
    __builtin_amdgcn_sched_barrier(0);
    {
        const char* vs = vgb + (size_t)kb0 * 128;
        gl16(vs, stV);
        gl16(vs + 16, stV + 1024);
    }
    __builtin_amdgcn_sched_barrier(0);
    m01 = *(const half8*)mbase;
    m23 = *(const half8*)(mbase + 8);
    __builtin_amdgcn_sched_barrier(0);
    {
        const char* ks = kgb + (size_t)(kb0 + 1) * 12288;
        gl16(ks, stW + 3072);
        gl16(ks + 64, stW + 3072 + 1024);
        gl16(ks + 128, stW + 3072 + 2048);
    }
    __builtin_amdgcn_sched_barrier(0);

    int ksl = 0;    // K slot of tile j
    int cur = 0;    // V slot of tile j
    for (int j = kb0; j < kbE; j++) {
        // Completes exactly {K(j), V(j), mask(j)}; K(j+1) (3 ops) stays in flight.
        asm volatile("s_waitcnt vmcnt(3)" ::: "memory");
        __builtin_amdgcn_sched_barrier(0);

        // LDS -> register fragments for tile j
        const char* kl = stW + ksl * 3072;
        half8 kf[3];
        kf[0] = *(const half8*)(kl + lane * 16);
        kf[1] = *(const half8*)(kl + 1024 + lane * 16);
        kf[2] = *(const half8*)(kl + 2048 + lane * 16);
        const char* vl = stV + cur * 2048 + (quad >> 1) * 1024 + l15 * 16 + (quad & 1) * 8;
        half4 vf[4];
        vf[0] = *(const half4*)(vl);
        vf[1] = *(const half4*)(vl + 256);
        vf[2] = *(const half4*)(vl + 512);
        vf[3] = *(const half4*)(vl + 768);

        // Unpack tile-j mask into temps BEFORE m01/m23 are reloaded for j+1.
        half2 mh[8];
        for (int i = 0; i < 4; i++) {
            mh[i]     = half2{m01[2 * i], m01[2 * i + 1]};
            mh[4 + i] = half2{m23[2 * i], m23[2 * i + 1]};
        }
        __builtin_amdgcn_sched_barrier(0);

        // V(j+1) DMA (unclamped; tail reads land in workspace pad)
        {
            const char* vs = vgb + (size_t)(j + 1) * 128;
            char* vd = stV + (cur ^ 1) * 2048;
            gl16(vs, vd);
            gl16(vs + 16, vd + 1024);
        }
        __builtin_amdgcn_sched_barrier(0);
        // mask(j+1) register loads (between V and K in the vmcnt queue)
        {
            const _Float16* mp = mbase + (size_t)(j + 1 - kb0) * 4096;
            m01 = *(const half8*)mp;
            m23 = *(const half8*)(mp + 8);
        }
        __builtin_amdgcn_sched_barrier(0);
        // K(j+2) DMA into the third slot (distance-2 lead)
        {
            const char* ks = kgb + (size_t)(j + 2) * 12288;
            char* kd = stW + ((ksl + 2) % 3) * 3072;
            gl16(ks, kd);
            gl16(ks + 64, kd + 1024);
            gl16(ks + 128, kd + 2048);
        }
        __builtin_amdgcn_sched_barrier(0);

        // S^T = K Q^T (C-init = -ESHIFT)
        f32x4 sT[4];
        for (int nt = 0; nt < 4; nt++) {
            f32x4 s = __builtin_amdgcn_mfma_f32_16x16x32_f16(kf[0], qf[0][nt], minit, 0, 0, 0);
            s = __builtin_amdgcn_mfma_f32_16x16x32_f16(kf[1], qf[1][nt], s, 0, 0, 0);
            s = __builtin_amdgcn_mfma_f32_16x16x32_f16(kf[2], qf[2][nt], s, 0, 0, 0);
            sT[nt] = s;
        }

        // p = exp2(s-8) via raw v_exp_f32; lsum; af = f16(p) * mask (mh copy)
        half4 af[4];
        for (int nt = 0; nt < 4; nt++) {
            float p0 = __builtin_amdgcn_exp2f(sT[nt][0]);
            float p1 = __builtin_amdgcn_exp2f(sT[nt][1]);
            float p2 = __builtin_amdgcn_exp2f(sT[nt][2]);
            float p3 = __builtin_amdgcn_exp2f(sT[nt][3]);
            lsum[nt] += (p0 + p1) + (p2 + p3);
            half2 lo = pk_cvt(p0, p1) * mh[2 * nt];
            half2 hi = pk_cvt(p2, p3) * mh[2 * nt + 1];
            af[nt] = half4{lo[0], lo[1], hi[0], hi[1]};
        }

        // O += P V
        for (int nt = 0; nt < 4; nt++)
            for (int v = 0; v < 4; v++)
                oacc[nt][v] = __builtin_amdgcn_mfma_f32_16x16x16f16(af[nt], vf[v], oacc[nt][v], 0, 0, 0);

        ksl = (ksl + 1) == 3 ? 0 : ksl + 1;
        cur ^= 1;
    }

    // Alias boundary: all waves done with staging LDS before Ob/Lb reuse.
    // (__syncthreads drains vmcnt(0) -> pending tail DMAs land before reuse.)
    __syncthreads();

    float (*Ob)[64][68] = (float (*)[64][68])smem;
    float (*Lb)[64] = (float (*)[64])(smem + 34816);

    for (int nt = 0; nt < 4; nt++) {
        lsum[nt] += __shfl_xor(lsum[nt], 16);
        lsum[nt] += __shfl_xor(lsum[nt], 32);
    }

    if (w & 1) {
        for (int nt = 0; nt < 4; nt++) {
            for (int v = 0; v < 4; v++)
                for (int r = 0; r < 4; r++)
                    Ob[w >> 1][16 * nt + 4 * quad + r][16 * v + l15] = oacc[nt][v][r];
            if (quad == 0) Lb[w >> 1][16 * nt + l15] = lsum[nt];
        }
    }
    __syncthreads();
    if (!(w & 1)) {
        for (int nt = 0; nt < 4; nt++) {
            for (int v = 0; v < 4; v++)
                for (int r = 0; r < 4; r++)
                    Ob[w >> 1][16 * nt + 4 * quad + r][16 * v + l15] += oacc[nt][v][r];
            if (quad == 0) Lb[w >> 1][16 * nt + l15] += lsum[nt];
        }
    }
    __syncthreads();

    {
        int row = t >> 2, c0 = (t & 3) * 16;
        _Float16* obase = Owsh + (size_t)z * N_SEQ * 512 + (size_t)(q0 + row) * 512
                          + head * HD_V + c0;
        for (int g = 0; g < 2; g++) {
            half8 h;
            for (int j2 = 0; j2 < 8; j2++)
                h[j2] = (_Float16)(Ob[0][row][c0 + 8 * g + j2] + Ob[1][row][c0 + 8 * g + j2]);
            *(half8*)(obase + 8 * g) = h;
        }
        if (t < 64)
            Lws[((size_t)z * NHEADS + head) * N_SEQ + q0 + t] = Lb[0][t] + Lb[1][t];
    }
}

// ---------------------------------------------------------------------------
// Finalize: out = sum_z O_z / (sum_z l_z * H * Msum[q])
// ---------------------------------------------------------------------------
__global__ __launch_bounds__(256) void finalize(
    const _Float16* __restrict__ Owsh, const float* __restrict__ Lws,
    const float* __restrict__ Msum, float* __restrict__ out)
{
    const size_t ZSTR = (size_t)N_SEQ * 512;
    size_t o = ((size_t)blockIdx.x * 256 + threadIdx.x) * 8;
    int q = (int)(o >> 9);
    int head = (int)((o & 511) >> 6);
    half8 p0 = *(const half8*)(Owsh + o);
    half8 p1 = *(const half8*)(Owsh + ZSTR + o);
    half8 p2 = *(const half8*)(Owsh + 2 * ZSTR + o);
    float l = Lws[(size_t)head * N_SEQ + q]
            + Lws[((size_t)NHEADS + head) * N_SEQ + q]
            + Lws[((size_t)2 * NHEADS + head) * N_SEQ + q];
    float inv = 1.0f / (l * (float)NHEADS * Msum[q]);
    float4 r0, r1;
    r0.x = ((float)p0[0] + (float)p1[0] + (float)p2[0]) * inv;
    r0.y = ((float)p0[1] + (float)p1[1] + (float)p2[1]) * inv;
    r0.z = ((float)p0[2] + (float)p1[2] + (float)p2[2]) * inv;
    r0.w = ((float)p0[3] + (float)p1[3] + (float)p2[3]) * inv;
    r1.x = ((float)p0[4] + (float)p1[4] + (float)p2[4]) * inv;
    r1.y = ((float)p0[5] + (float)p1[5] + (float)p2[5]) * inv;
    r1.z = ((float)p0[6] + (float)p1[6] + (float)p2[6]) * inv;
    r1.w = ((float)p0[7] + (float)p1[7] + (float)p2[7]) * inv;
    *(float4*)(out + o) = r0;
    *(float4*)(out + o + 4) = r1;
}

extern "C" void kernel_launch(void* const* d_in, const int* in_sizes, int n_in,
                              void* d_out, int out_size, void* d_ws, size_t ws_size,
                              hipStream_t stream) {
    const float* qk    = (const float*)d_in[0];
    const float* v_cls = (const float*)d_in[1];
    const float* masks = (const float*)d_in[2];
    const float* W_qk  = (const float*)d_in[3];
    const float* W_v   = (const float*)d_in[4];
    float* out = (float*)d_out;

    char* wsp = (char*)d_ws;
    // region0 [0, 13 MB): prep-stage buffers, later aliased by Owsh (12.6 MB)
    _Float16* Xh   = (_Float16*)(wsp);                         // 6.0 MB
    _Float16* Vch  = (_Float16*)(wsp + (size_t)6291456);       // 4.0 MB
    _Float16* Wqkt = (_Float16*)(wsp + (size_t)10485760);      // 2.25 MB
    _Float16* Wvt  = (_Float16*)(wsp + (size_t)12845056);      // 0.5 MB
    _Float16* Owsh = (_Float16*)(wsp);                         // 3*4096*512*2 = 12.58 MB
    size_t off = 13631488;                                     // 13 MB
    auto allocB = [&](size_t bytes) { char* p = wsp + off; off += (bytes + 255) & ~(size_t)255; return p; };
    _Float16* Qh   = (_Float16*)allocB((size_t)NHEADS * N_SEQ * HD_QK * 2);
    _Float16* Kh   = (_Float16*)allocB((size_t)NHEADS * N_SEQ * HD_QK * 2);
    _Float16* Vtg  = (_Float16*)allocB((size_t)NHEADS * HD_V * N_SEQ * 2);
    _Float16* Msw  = (_Float16*)allocB((size_t)N_SEQ * N_SEQ * 2);
    float*    Msum = (float*)allocB((size_t)N_SEQ * 4);
    float*    Lws  = (float*)allocB((size_t)3 * NHEADS * N_SEQ * 4);
    // tail pad: unclamped K(j+2)/V(j+1)/mask(j+1) prefetches may read up to
    // ~64KB past their buffers -- keep them inside the workspace.
    (void)allocB((size_t)131072);
    (void)ws_size;

    dim3 blk(256);
    (void)hipMemsetAsync(Msum, 0, N_SEQ * sizeof(float), stream);
    prep<<<dim3(8064), blk, 0, stream>>>(
        qk, v_cls, masks, W_qk, W_v, Xh, Vch, Msw, Msum, Wqkt, Wvt);

    proj_fused<<<dim3(32, N_SEQ / 128), blk, 0, stream>>>(
        Xh, Vch, Wqkt, Wvt, Qh, Kh, Vtg);

    flash_attn<<<dim3(1536), blk, 0, stream>>>(
        Qh, Kh, Vtg, Msw, Owsh, Lws);

    finalize<<<dim3((N_SEQ * 512) / (256 * 8)), blk, 0, stream>>>(
        Owsh, Lws, Msum, out);
}

// Round 16
// 249.758 us; speedup vs baseline: 2.2820x; 1.2599x over previous
//
#include <hip/hip_runtime.h>

typedef __attribute__((ext_vector_type(8))) _Float16 half8;
typedef __attribute__((ext_vector_type(4))) _Float16 half4;
typedef __attribute__((ext_vector_type(2))) _Float16 half2;
typedef __attribute__((ext_vector_type(2))) __fp16 fp16x2;
typedef __attribute__((ext_vector_type(4))) float f32x4;

#define N_SEQ 4096
#define HD_QK 96
#define HD_V  64
#define NHEADS 8
// Q pre-scale = (256/8)^-0.5 * log2(e) -> scores in log2 domain
#define QSCALE 0.25505545556f
#define ESHIFT 8.0f

union PKC { fp16x2 p; half2 h; };

__device__ inline half2 pk_cvt(float a, float b) {
    PKC u;
    u.p = __builtin_amdgcn_cvt_pkrtz(a, b);
    return u.h;
}

__device__ inline half8 cvt8(float4 a, float4 b) {
    half8 h;
    h[0] = (_Float16)a.x; h[1] = (_Float16)a.y; h[2] = (_Float16)a.z; h[3] = (_Float16)a.w;
    h[4] = (_Float16)b.x; h[5] = (_Float16)b.y; h[6] = (_Float16)b.z; h[7] = (_Float16)b.w;
    return h;
}

__device__ inline void cast_blk(const float* __restrict__ in, _Float16* __restrict__ out,
                                int blk, int t) {
    size_t i = ((size_t)blk * 256 + t) * 8;
    float4 a = *(const float4*)(in + i);
    float4 b = *(const float4*)(in + i + 4);
    *(half8*)(out + i) = cvt8(a, b);
}

// 16B-per-lane global -> LDS DMA. LDS dest = uniform base + lane*16 (HW rule);
// global src is per-lane.
__device__ __forceinline__ void gl16(const void* g, void* l) {
    __builtin_amdgcn_global_load_lds(
        (const __attribute__((address_space(1))) unsigned int*)g,
        (__attribute__((address_space(3))) unsigned int*)l, 16, 0, 0);
}

// ---------------------------------------------------------------------------
// Prep (one launch):
//  [0,1536)     qk -> Xh f16
//  [1536,2560)  v_cls -> Vch f16
//  [2560,3712)  W_qk^T f16
//  [3712,3968)  W_v^T f16
//  [3968,8064)  masks -> swizzled f16 Msw (COALESCED writes) + Msum atomics
// One block per 64x64 mask tile (q0b,kb) == one contiguous 8KB Msw chunk.
// Msw layout (halves), flash-r4-verbatim:
//   ((q0b*64+kb)*4 + w)*1024 + l15*64 + quad*16 + nt*4 + j
//   holds M[q0b*64 + 16nt + l15][kb*64 + 16w + 4quad + j]
// Row sums: LDS-reduce 16 partials/row -> 64 atomicAdds per block.
// ---------------------------------------------------------------------------
__global__ __launch_bounds__(256) void prep(
    const float* __restrict__ qk, const float* __restrict__ v_cls,
    const float* __restrict__ masks, const float* __restrict__ W_qk,
    const float* __restrict__ W_v,
    _Float16* __restrict__ Xh, _Float16* __restrict__ Vch,
    _Float16* __restrict__ Msw, float* __restrict__ Msum,
    _Float16* __restrict__ Wqkt, _Float16* __restrict__ Wvt)
{
    __shared__ float tile[32][33];
    __shared__ float red[64][17];
    const int bx = blockIdx.x, t = threadIdx.x;
    if (bx < 1536) {
        cast_blk(qk, Xh, bx, t);
    } else if (bx < 2560) {
        cast_blk(v_cls, Vch, bx - 1536, t);
    } else if (bx < 3968) {
        const bool big = bx < 3712;
        const int id = big ? bx - 2560 : bx - 3712;
        const int nx = big ? 48 : 16;
        const int C = big ? 1536 : 512, R = big ? 768 : 512;
        const float* in = big ? W_qk : W_v;
        _Float16* out = big ? Wqkt : Wvt;
        int cx = id % nx, cy = id / nx;
        int tx = t & 31, ty = t >> 5;
        int c0 = cx * 32, r0 = cy * 32;
        for (int k = 0; k < 4; k++)
            tile[ty + 8 * k][tx] = in[(size_t)(r0 + ty + 8 * k) * C + c0 + tx];
        __syncthreads();
        for (int k = 0; k < 4; k++)
            out[(size_t)(c0 + ty + 8 * k) * R + r0 + tx] = (_Float16)tile[tx][ty + 8 * k];
    } else {
        const int id = bx - 3968;             // [0,4096): 64x64 mask tile
        const int q0b = id >> 6, kb = id & 63;
        const int w = t >> 6, lane = t & 63;
        const int l15 = lane >> 2, quad = lane & 3;
        const int col = kb * 64 + 16 * w + 4 * quad;
        half4 hv[4];
        float ps[4];
        for (int nt = 0; nt < 4; nt++) {
            const float* src = masks + (size_t)(q0b * 64 + 16 * nt + l15) * N_SEQ + col;
            float4 a = *(const float4*)src;
            hv[nt] = half4{(_Float16)a.x, (_Float16)a.y, (_Float16)a.z, (_Float16)a.w};
            ps[nt] = (a.x + a.y) + (a.z + a.w);
        }
        _Float16* dst = Msw + (((size_t)(q0b * 64 + kb) * 4 + w) * 1024) + lane * 16;
        half8 h0, h1;
        for (int j = 0; j < 4; j++) {
            h0[j] = hv[0][j]; h0[4 + j] = hv[1][j];
            h1[j] = hv[2][j]; h1[4 + j] = hv[3][j];
        }
        *(half8*)dst = h0;
        *(half8*)(dst + 8) = h1;
        for (int nt = 0; nt < 4; nt++)
            red[16 * nt + l15][w * 4 + quad] = ps[nt];
        __syncthreads();
        if (t < 64) {
            float s = 0.f;
            for (int i = 0; i < 16; i++) s += red[t][i];
            atomicAdd(&Msum[q0b * 64 + t], s);
        }
    }
}

// ---------------------------------------------------------------------------
// Fused projection GEMM (f16 in), 128x64 tile, BK=64.
// Grid 32x32 = 1024 blocks = 4 blocks/CU. acc 4x2 (32 AGPR), LDS 27.6 KB.
// blockIdx.x < 24: Xh@Wqkt^T (N=1536) -> Qh (xQSCALE) / Kh
// else:            Vch@Wvt^T (N=512)  -> Vtg[h][d][n]
// ---------------------------------------------------------------------------
__global__ __launch_bounds__(256) void proj_fused(
    const _Float16* __restrict__ Xh, const _Float16* __restrict__ Vch,
    const _Float16* __restrict__ Wqkt, const _Float16* __restrict__ Wvt,
    _Float16* __restrict__ Qh, _Float16* __restrict__ Kh,
    _Float16* __restrict__ Vtg)
{
    __shared__ _Float16 smem[192 * 72];   // Xs 128x72 + Ws 64x72 = 27.6 KB
    _Float16 (*Xs)[72] = (_Float16 (*)[72])smem;
    _Float16 (*Ws)[72] = (_Float16 (*)[72])(smem + 128 * 72);

    const int t = threadIdx.x;
    const int lane = t & 63, wv = t >> 6;
    const int quad = lane >> 4, l15 = lane & 15;
    const bool qkmode = blockIdx.x < 24;
    const int n0 = qkmode ? blockIdx.x * 64 : (blockIdx.x - 24) * 64;
    const int row0 = blockIdx.y * 128;
    const int K = qkmode ? 768 : 512;
    const _Float16* X = qkmode ? Xh : Vch;
    const _Float16* Wt = qkmode ? Wqkt : Wvt;

    const int mB = (wv & 1) * 64, nB = (wv >> 1) * 32;
    const int sr = t >> 1, sk = (t & 1) * 32;      // X stage: 128 rows x 64
    const int sr2 = t >> 2, sk2 = (t & 3) * 16;    // W stage: 64 rows x 64

    const f32x4 fzero = {0.f, 0.f, 0.f, 0.f};
    f32x4 acc[4][2];
    for (int i = 0; i < 4; i++)
        for (int j = 0; j < 2; j++) acc[i][j] = fzero;

    for (int k0 = 0; k0 < K; k0 += 64) {
        __syncthreads();
        {
            const _Float16* xp = X + (size_t)(row0 + sr) * K + k0 + sk;
            *(half8*)&Xs[sr][sk]      = *(const half8*)xp;
            *(half8*)&Xs[sr][sk + 8]  = *(const half8*)(xp + 8);
            *(half8*)&Xs[sr][sk + 16] = *(const half8*)(xp + 16);
            *(half8*)&Xs[sr][sk + 24] = *(const half8*)(xp + 24);
            const _Float16* wp = Wt + (size_t)(n0 + sr2) * K + k0 + sk2;
            *(half8*)&Ws[sr2][sk2]     = *(const half8*)wp;
            *(half8*)&Ws[sr2][sk2 + 8] = *(const half8*)(wp + 8);
        }
        __syncthreads();
        for (int c = 0; c < 2; c++) {
            half8 af[4], bf[2];
            for (int i = 0; i < 4; i++)
                af[i] = *(const half8*)&Xs[mB + 16 * i + l15][c * 32 + quad * 8];
            for (int j = 0; j < 2; j++)
                bf[j] = *(const half8*)&Ws[nB + 16 * j + l15][c * 32 + quad * 8];
            for (int i = 0; i < 4; i++)
                for (int j = 0; j < 2; j++)
                    acc[i][j] = __builtin_amdgcn_mfma_f32_16x16x32_f16(af[i], bf[j], acc[i][j], 0, 0, 0);
        }
    }

    __syncthreads();
    _Float16 (*Ct)[72] = (_Float16 (*)[72])smem;   // 128 x 72 f16 (reuse)
    for (int j = 0; j < 2; j++) {
        int col = n0 + nB + 16 * j + l15;
        float scl = (qkmode && col < 768) ? QSCALE : 1.0f;
        for (int i = 0; i < 4; i++)
            for (int r = 0; r < 4; r++)
                Ct[mB + 16 * i + quad * 4 + r][nB + 16 * j + l15] =
                    (_Float16)(acc[i][j][r] * scl);
    }
    __syncthreads();

    if (qkmode) {
        for (int e = 0; e < 4; e++) {
            int id = e * 256 + t;
            int row = id >> 3, cc = id & 7;       // 128 rows x 8 col-groups
            int col = n0 + cc * 8;
            int w = col >= 768 ? 1 : 0;
            int rem = col - w * 768;
            int h = rem / 96, d = rem - h * 96;
            _Float16* dst = w ? Kh : Qh;
            *(half8*)&dst[((size_t)h * N_SEQ + row0 + row) * HD_QK + d] =
                *(const half8*)&Ct[row][cc * 8];
        }
    } else {
        for (int e = 0; e < 2; e++) {
            int id = e * 256 + t;
            int col = id >> 3, rc = id & 7;       // 64 cols x 8 row-groups
            int c = n0 + col;
            int h = c >> 6, d = c & 63;
            half8 v0, v1;
            for (int k = 0; k < 8; k++) {
                v0[k] = Ct[rc * 16 + k][col];
                v1[k] = Ct[rc * 16 + 8 + k][col];
            }
            _Float16* dst = &Vtg[((size_t)h * HD_V + d) * N_SEQ + row0 + rc * 16];
            *(half8*)dst = v0;
            *(half8*)(dst + 8) = v1;
        }
    }
}

// ---------------------------------------------------------------------------
// Flash attention (r12-verbatim, the proven 106.5us configuration):
// q0b-major XCD pinning (r11 proved head-major loses mask L2 reuse).
// Raw v_exp_f32 + unclamped j+1 prefetch (r12: VALUBusy 37->26.6, -16us).
// Split-K z=3 (grid 1536, 3 blk/CU; r8 proved 4 blk/CU spills; r14/r15
// proved deeper prefetch spills or defeats the scheduler). Wave-private
// double-buffered LDS staging via global_load_lds DMA; no barriers in
// loop; one s_waitcnt vmcnt(2)/iter. -ESHIFT folded into MFMA C-init.
// ---------------------------------------------------------------------------
__global__ __launch_bounds__(256, 3) void flash_attn(
    const _Float16* __restrict__ Qh, const _Float16* __restrict__ Kh,
    const _Float16* __restrict__ Vtg, const _Float16* __restrict__ Msw,
    _Float16* __restrict__ Owsh, float* __restrict__ Lws)
{
    // [0, 40960): staging, per wave w at w*10240: buf b at b*5120:
    //   K[16 rows][96 halves] lane-linear (3072 B), V chunks (2048 B)
    // epilogue alias: Ob[2][64][68] f32 at 0 (34816 B), Lb[2][64] at 34816
    __shared__ __align__(16) char smem[40960];

    const int t = threadIdx.x;
    const int lane = t & 63, w = t >> 6;
    const int quad = lane >> 4, l15 = lane & 15;
    const int bx = blockIdx.x;
    const int q0b = bx & 63;
    const int hz = bx >> 6;
    const int head = hz & 7;
    const int z = hz >> 3;
    const int q0 = q0b * 64;
    const int kb0 = 21 * z, kbE = (z == 2) ? 64 : kb0 + 21;

    half8 qf[3][4];
    for (int nt = 0; nt < 4; nt++) {
        const _Float16* qp = Qh + ((size_t)head * N_SEQ + q0 + 16 * nt + l15) * HD_QK + 8 * quad;
        for (int c = 0; c < 3; c++)
            qf[c][nt] = *(const half8*)(qp + 32 * c);
    }

    // per-lane global source bases (bytes)
    const char* kgb = (const char*)Kh
        + ((size_t)(head * N_SEQ + 16 * w + l15) * HD_QK + 8 * quad) * 2;
    const char* vgb = (const char*)Vtg
        + ((size_t)(head * HD_V + lane) * N_SEQ) * 2 + 32 * w;
    const _Float16* mbase = Msw + ((size_t)(q0b * 64 + kb0) * 4 + w) * 1024
                                + (l15 * 4 + quad) * 16;

    char* stW = smem + w * 10240;   // this wave's private staging

    const f32x4 fzero = {0.f, 0.f, 0.f, 0.f};
    const f32x4 minit = {-ESHIFT, -ESHIFT, -ESHIFT, -ESHIFT};
    f32x4 oacc[4][4];
    for (int nt = 0; nt < 4; nt++)
        for (int v = 0; v < 4; v++) oacc[nt][v] = fzero;
    float lsum[4] = {0.f, 0.f, 0.f, 0.f};

    half8 m01, m23;

    // Prologue: DMA tile kb0 into buf0 (5 ops), then mask(kb0) reg loads (2 ops)
    {
        char* kd = stW;
        const char* ks = kgb + (size_t)kb0 * 12288;
        gl16(ks, kd);
        gl16(ks + 64, kd + 1024);
        gl16(ks + 128, kd + 2048);
        char* vd = stW + 3072;
        const char* vs = vgb + (size_t)kb0 * 128;
        gl16(vs, vd);
        gl16(vs + 16, vd + 1024);
    }
    m01 = *(const half8*)mbase;
    m23 = *(const half8*)(mbase + 8);

    int cur = 0;
    for (int j = kb0; j < kbE; j++, cur ^= 1) {
        // Force previous tile's DMAs complete; allow the 2 mask loads in flight.
        asm volatile("s_waitcnt vmcnt(2)" ::: "memory");
        __builtin_amdgcn_sched_barrier(0);

        // LDS -> register fragments for tile j (lane-linear K; V chunk layout)
        const char* kl = stW + cur * 5120;
        half8 kf[3];
        kf[0] = *(const half8*)(kl + lane * 16);
        kf[1] = *(const half8*)(kl + 1024 + lane * 16);
        kf[2] = *(const half8*)(kl + 2048 + lane * 16);
        const char* vl = kl + 3072 + (quad >> 1) * 1024 + l15 * 16 + (quad & 1) * 8;
        half4 vf[4];
        vf[0] = *(const half4*)(vl);
        vf[1] = *(const half4*)(vl + 256);
        vf[2] = *(const half4*)(vl + 512);
        vf[3] = *(const half4*)(vl + 768);

        // DMA tile j+1 UNCLAMPED into the other buffer (final prefetch lands
        // in never-consumed ws bytes; all addresses stay inside workspace)
        const int jn = j + 1;
        {
            char* kd = stW + (cur ^ 1) * 5120;
            const char* ks = kgb + (size_t)jn * 12288;
            gl16(ks, kd);
            gl16(ks + 64, kd + 1024);
            gl16(ks + 128, kd + 2048);
            char* vd = kd + 3072;
            const char* vs = vgb + (size_t)jn * 128;
            gl16(vs, vd);
            gl16(vs + 16, vd + 1024);
        }

        // S^T = K Q^T (C-init = -ESHIFT)
        f32x4 sT[4];
        for (int nt = 0; nt < 4; nt++) {
            f32x4 s = __builtin_amdgcn_mfma_f32_16x16x32_f16(kf[0], qf[0][nt], minit, 0, 0, 0);
            s = __builtin_amdgcn_mfma_f32_16x16x32_f16(kf[1], qf[1][nt], s, 0, 0, 0);
            s = __builtin_amdgcn_mfma_f32_16x16x32_f16(kf[2], qf[2][nt], s, 0, 0, 0);
            sT[nt] = s;
        }

        // p = exp2(s-8) via raw v_exp_f32; lsum; af = f16(p) * mask
        half4 af[4];
        {
            half2 mh[8];
            for (int i = 0; i < 4; i++) {
                mh[i]     = half2{m01[2 * i], m01[2 * i + 1]};
                mh[4 + i] = half2{m23[2 * i], m23[2 * i + 1]};
            }
            for (int nt = 0; nt < 4; nt++) {
                float p0 = __builtin_amdgcn_exp2f(sT[nt][0]);
                float p1 = __builtin_amdgcn_exp2f(sT[nt][1]);
                float p2 = __builtin_amdgcn_exp2f(sT[nt][2]);
                float p3 = __builtin_amdgcn_exp2f(sT[nt][3]);
                lsum[nt] += (p0 + p1) + (p2 + p3);
                half2 lo = pk_cvt(p0, p1) * mh[2 * nt];
                half2 hi = pk_cvt(p2, p3) * mh[2 * nt + 1];
                af[nt] = half4{lo[0], lo[1], hi[0], hi[1]};
            }
        }
        // mask(jn) register prefetch (the 2 loads vmcnt(2) tolerates)
        {
            const _Float16* mp = mbase + (size_t)(jn - kb0) * 4096;
            m01 = *(const half8*)mp;
            m23 = *(const half8*)(mp + 8);
        }

        // O += P V
        for (int nt = 0; nt < 4; nt++)
            for (int v = 0; v < 4; v++)
                oacc[nt][v] = __builtin_amdgcn_mfma_f32_16x16x16f16(af[nt], vf[v], oacc[nt][v], 0, 0, 0);
    }

    // Alias boundary: all waves done with staging LDS before Ob/Lb reuse.
    __syncthreads();

    float (*Ob)[64][68] = (float (*)[64][68])smem;
    float (*Lb)[64] = (float (*)[64])(smem + 34816);

    for (int nt = 0; nt < 4; nt++) {
        lsum[nt] += __shfl_xor(lsum[nt], 16);
        lsum[nt] += __shfl_xor(lsum[nt], 32);
    }

    if (w & 1) {
        for (int nt = 0; nt < 4; nt++) {
            for (int v = 0; v < 4; v++)
                for (int r = 0; r < 4; r++)
                    Ob[w >> 1][16 * nt + 4 * quad + r][16 * v + l15] = oacc[nt][v][r];
            if (quad == 0) Lb[w >> 1][16 * nt + l15] = lsum[nt];
        }
    }
    __syncthreads();
    if (!(w & 1)) {
        for (int nt = 0; nt < 4; nt++) {
            for (int v = 0; v < 4; v++)
                for (int r = 0; r < 4; r++)
                    Ob[w >> 1][16 * nt + 4 * quad + r][16 * v + l15] += oacc[nt][v][r];
            if (quad == 0) Lb[w >> 1][16 * nt + l15] += lsum[nt];
        }
    }
    __syncthreads();

    {
        int row = t >> 2, c0 = (t & 3) * 16;
        _Float16* obase = Owsh + (size_t)z * N_SEQ * 512 + (size_t)(q0 + row) * 512
                          + head * HD_V + c0;
        for (int g = 0; g < 2; g++) {
            half8 h;
            for (int j2 = 0; j2 < 8; j2++)
                h[j2] = (_Float16)(Ob[0][row][c0 + 8 * g + j2] + Ob[1][row][c0 + 8 * g + j2]);
            *(half8*)(obase + 8 * g) = h;
        }
        if (t < 64)
            Lws[((size_t)z * NHEADS + head) * N_SEQ + q0 + t] = Lb[0][t] + Lb[1][t];
    }
}

// ---------------------------------------------------------------------------
// Finalize: out = sum_z O_z / (sum_z l_z * H * Msum[q])
// ---------------------------------------------------------------------------
__global__ __launch_bounds__(256) void finalize(
    const _Float16* __restrict__ Owsh, const float* __restrict__ Lws,
    const float* __restrict__ Msum, float* __restrict__ out)
{
    const size_t ZSTR = (size_t)N_SEQ * 512;
    size_t o = ((size_t)blockIdx.x * 256 + threadIdx.x) * 8;
    int q = (int)(o >> 9);
    int head = (int)((o & 511) >> 6);
    half8 p0 = *(const half8*)(Owsh + o);
    half8 p1 = *(const half8*)(Owsh + ZSTR + o);
    half8 p2 = *(const half8*)(Owsh + 2 * ZSTR + o);
    float l = Lws[(size_t)head * N_SEQ + q]
            + Lws[((size_t)NHEADS + head) * N_SEQ + q]
            + Lws[((size_t)2 * NHEADS + head) * N_SEQ + q];
    float inv = 1.0f / (l * (float)NHEADS * Msum[q]);
    float4 r0, r1;
    r0.x = ((float)p0[0] + (float)p1[0] + (float)p2[0]) * inv;
    r0.y = ((float)p0[1] + (float)p1[1] + (float)p2[1]) * inv;
    r0.z = ((float)p0[2] + (float)p1[2] + (float)p2[2]) * inv;
    r0.w = ((float)p0[3] + (float)p1[3] + (float)p2[3]) * inv;
    r1.x = ((float)p0[4] + (float)p1[4] + (float)p2[4]) * inv;
    r1.y = ((float)p0[5] + (float)p1[5] + (float)p2[5]) * inv;
    r1.z = ((float)p0[6] + (float)p1[6] + (float)p2[6]) * inv;
    r1.w = ((float)p0[7] + (float)p1[7] + (float)p2[7]) * inv;
    *(float4*)(out + o) = r0;
    *(float4*)(out + o + 4) = r1;
}

extern "C" void kernel_launch(void* const* d_in, const int* in_sizes, int n_in,
                              void* d_out, int out_size, void* d_ws, size_t ws_size,
                              hipStream_t stream) {
    const float* qk    = (const float*)d_in[0];
    const float* v_cls = (const float*)d_in[1];
    const float* masks = (const float*)d_in[2];
    const float* W_qk  = (const float*)d_in[3];
    const float* W_v   = (const float*)d_in[4];
    float* out = (float*)d_out;

    char* wsp = (char*)d_ws;
    // region0 [0, 13 MB): prep-stage buffers, later aliased by Owsh (12.6 MB)
    _Float16* Xh   = (_Float16*)(wsp);                         // 6.0 MB
    _Float16* Vch  = (_Float16*)(wsp + (size_t)6291456);       // 4.0 MB
    _Float16* Wqkt = (_Float16*)(wsp + (size_t)10485760);      // 2.25 MB
    _Float16* Wvt  = (_Float16*)(wsp + (size_t)12845056);      // 0.5 MB
    _Float16* Owsh = (_Float16*)(wsp);                         // 3*4096*512*2 = 12.58 MB
    size_t off = 13631488;                                     // 13 MB
    auto allocB = [&](size_t bytes) { char* p = wsp + off; off += (bytes + 255) & ~(size_t)255; return p; };
    _Float16* Qh   = (_Float16*)allocB((size_t)NHEADS * N_SEQ * HD_QK * 2);
    _Float16* Kh   = (_Float16*)allocB((size_t)NHEADS * N_SEQ * HD_QK * 2);
    _Float16* Vtg  = (_Float16*)allocB((size_t)NHEADS * HD_V * N_SEQ * 2);
    _Float16* Msw  = (_Float16*)allocB((size_t)N_SEQ * N_SEQ * 2);
    float*    Msum = (float*)allocB((size_t)N_SEQ * 4);
    float*    Lws  = (float*)allocB((size_t)3 * NHEADS * N_SEQ * 4);
    // tail pad so the unclamped final prefetch (<= 12.3KB past Msw region
    // users) stays inside the workspace:
    (void)allocB((size_t)16384);
    (void)ws_size;

    dim3 blk(256);
    (void)hipMemsetAsync(Msum, 0, N_SEQ * sizeof(float), stream);
    prep<<<dim3(8064), blk, 0, stream>>>(
        qk, v_cls, masks, W_qk, W_v, Xh, Vch, Msw, Msum, Wqkt, Wvt);

    proj_fused<<<dim3(32, N_SEQ / 128), blk, 0, stream>>>(
        Xh, Vch, Wqkt, Wvt, Qh, Kh, Vtg);

    flash_attn<<<dim3(1536), blk, 0, stream>>>(
        Qh, Kh, Vtg, Msw, Owsh, Lws);

    finalize<<<dim3((N_SEQ * 512) / (256 * 8)), blk, 0, stream>>>(
        Owsh, Lws, Msum, out);
}